// Round 8
// baseline (21286.983 us; speedup 1.0000x reference)
//
#include <hip/hip_runtime.h>
#include <hip/hip_bf16.h>

// Problem: B=8, N=4096, C=256, c4=64. All fp32. P = B*N = 32768 points.
//
//  x0  = relu(feature @ conv0_w^T + b)            [P,64]
//  idx1 = knn12(x0);  EC1: h1=relu(u1[j]+v1[i]), h2=relu(h1@W2^T+b2), max_k -> x1 [P,256]
//  x1c = relu(x1 @ conv1_w^T + b)                 [P,64]
//  idx2 = knn8(x1c);  EC2: x2 = sum_k relu(u2[j]+v2[i])  [P,256]
//  decoder: 256->128->64->1 (all relu)
//
// u/v decomposition: W=[A|B]: edge(o) = x_j.A[o] + x_i.(B[o]-A[o]) = u[j][o] + v[i][o]

#define PTS_TOTAL 32768
#define NPTS 4096
#define NBATCH 8

// ---------------------------------------------------------------- prep weights
__global__ void prep_kernel(const float* __restrict__ w1, const float* __restrict__ b1,
                            const float* __restrict__ w2,
                            const float* __restrict__ ew, const float* __restrict__ eb,
                            float* __restrict__ wuv1, float* __restrict__ buv1,
                            float* __restrict__ wuv2, float* __restrict__ buv2,
                            float* __restrict__ w2t) {
  int tid = blockIdx.x * 256 + threadIdx.x;
  if (tid < 512 * 64) {
    int o = tid / 64, c = tid % 64;
    int orow = o & 255;
    float a  = w1[orow * 128 + c];
    float bb = w1[orow * 128 + 64 + c];
    wuv1[tid] = (o < 256) ? a : (bb - a);
    float a2  = ew[orow * 128 + c];
    float b2p = ew[orow * 128 + 64 + c];
    wuv2[tid] = (o < 256) ? a2 : (b2p - a2);
  }
  if (tid < 512) {
    buv1[tid] = (tid < 256) ? 0.f : b1[tid - 256];
    buv2[tid] = (tid < 256) ? 0.f : eb[tid - 256];
  }
  if (tid < 65536) {
    int o = tid / 256, c = tid % 256;
    w2t[c * 256 + o] = w2[o * 256 + c];
  }
}

// ---------------------------------------------------------------- generic fp32 GEMM
template<bool RELU>
__global__ __launch_bounds__(256) void gemm_rowmajor(
    const float* __restrict__ A, const float* __restrict__ W,
    const float* __restrict__ bias, float* __restrict__ Cmat,
    int M, int K, int Cout) {
  __shared__ __align__(16) float As[32][68];
  __shared__ __align__(16) float Bs[32][68];
  int m0 = blockIdx.x * 64;
  int n0 = blockIdx.y * 64;
  int tid = threadIdx.x;
  int tx = tid & 15, ty = tid >> 4;
  float acc[4][4] = {};
  for (int k0 = 0; k0 < K; k0 += 32) {
#pragma unroll
    for (int i = 0; i < 2; ++i) {
      int rr = (tid >> 3) + 32 * i;
      int cc = (tid & 7) * 4;
      float4 va = *(const float4*)&A[(size_t)(m0 + rr) * K + k0 + cc];
      float4 vb = *(const float4*)&W[(size_t)(n0 + rr) * K + k0 + cc];
      As[cc + 0][rr] = va.x; As[cc + 1][rr] = va.y; As[cc + 2][rr] = va.z; As[cc + 3][rr] = va.w;
      Bs[cc + 0][rr] = vb.x; Bs[cc + 1][rr] = vb.y; Bs[cc + 2][rr] = vb.z; Bs[cc + 3][rr] = vb.w;
    }
    __syncthreads();
#pragma unroll 8
    for (int k = 0; k < 32; ++k) {
      float4 a4 = *(const float4*)&As[k][ty * 4];
      float4 b4 = *(const float4*)&Bs[k][tx * 4];
      float a[4] = {a4.x, a4.y, a4.z, a4.w};
      float b[4] = {b4.x, b4.y, b4.z, b4.w};
#pragma unroll
      for (int ii = 0; ii < 4; ++ii)
#pragma unroll
        for (int jj = 0; jj < 4; ++jj)
          acc[ii][jj] += a[ii] * b[jj];
    }
    __syncthreads();
  }
  float4 bias4 = *(const float4*)&bias[n0 + tx * 4];
  float bv[4] = {bias4.x, bias4.y, bias4.z, bias4.w};
#pragma unroll
  for (int ii = 0; ii < 4; ++ii) {
    int m = m0 + ty * 4 + ii;
    float4 v4;
    float* vp = (float*)&v4;
#pragma unroll
    for (int jj = 0; jj < 4; ++jj) {
      float v = acc[ii][jj] + bv[jj];
      if (RELU) v = fmaxf(v, 0.f);
      vp[jj] = v;
    }
    *(float4*)&Cmat[(size_t)m * Cout + n0 + tx * 4] = v4;
  }
}

// ---------------------------------------------------------------- squared norms (C=64)
__global__ void sqnorm64(const float* __restrict__ X, float* __restrict__ xx) {
  int p = blockIdx.x * 4 + (threadIdx.x >> 6);
  int lane = threadIdx.x & 63;
  float v = X[(size_t)p * 64 + lane];
  float s = v * v;
#pragma unroll
  for (int off = 32; off >= 1; off >>= 1) s += __shfl_xor(s, off);
  if (lane == 0) xx[p] = s;
}

// ---------------------------------------------------------------- knn v7
// lane = query row (64 rows = 64 lanes); wave covers a 16-m subrange per tile.
//  - A row lives in registers (float4 areg[16]) -> zero per-tile A traffic.
//  - B reads are WAVE-UNIFORM -> LDS broadcast (runtime same-address, no
//    serialization) -> GEMM becomes VALU-bound, not LDS-bound (r6 lesson).
//  - top-K list lives in LDS [slot][tid] (bank=tid%32, 2-way=free). Dynamic
//    slot indexing is native in LDS -> cannot be demoted to scratch
//    (r3-r6 lesson: register arrays/scalars kept landing in scratch).
//  - register 'worst' caches the K-th best for the gate.
// Strict < everywhere; per-lane gi is monotonic -> reference tie semantics.
template<int KN>
__global__ __launch_bounds__(256, 3) void knn_kernel(
    const float* __restrict__ X,   // [B][N][64]
    const float* __restrict__ XX,  // [B][N]
    float* __restrict__ outD,      // [2][P][KN]
    int* __restrict__ outI) {      // [2][P][KN]
  constexpr int UNION_FL = (2 * KN * 256 > 4352) ? 2 * KN * 256 : 4352;
  __shared__ __align__(16) float smem[4352 + UNION_FL + 64];
  float4* Bs4 = (float4*)smem;            // [64 m][17 f4] (68-dword rows)
  float* uni = smem + 4352;               // A-stage, then top-K lists
  float4* As4 = (float4*)uni;             // [64 r][17 f4] during init
  float* ldsD = uni;                      // [KN][256]
  int* ldsI = (int*)(uni + KN * 256);     // [KN][256]
  float* xxs = smem + 4352 + UNION_FL;    // [64]

  int tid = threadIdx.x;
  int tx = tid & 15, ty = tid >> 4;       // staging map
  int lane = tid & 63;
  int w16 = (tid >> 6) << 4;              // wave's m-offset within tile
  int b = blockIdx.z;
  int split = blockIdx.y;
  int q0 = blockIdx.x * 64;
  int mbase = split * (NPTS / 2);
  const int NT = (NPTS / 2) / 64;
  const float* Xb = X + (size_t)b * NPTS * 64;
  const float* XXb = XX + (size_t)b * NPTS;

  // prefetch B tile 0
  float4 pre[4];
  float prex;
#pragma unroll
  for (int i = 0; i < 4; ++i)
    pre[i] = *(const float4*)&Xb[(size_t)(mbase + ty + 16 * i) * 64 + tx * 4];
  prex = XXb[mbase + lane];

  // stage A -> LDS (coalesced), then to per-lane registers
  {
#pragma unroll
    for (int i = 0; i < 4; ++i)
      As4[(ty + 16 * i) * 17 + tx] =
          *(const float4*)&Xb[(size_t)(q0 + ty + 16 * i) * 64 + tx * 4];
  }
  __syncthreads();
  float4 areg[16];
#pragma unroll
  for (int kb = 0; kb < 16; ++kb) areg[kb] = As4[lane * 17 + kb];
  __syncthreads();  // all A reads done before lists overwrite the region

  // init top-K lists (each thread owns column tid; no cross-thread use)
#pragma unroll
  for (int s = 0; s < KN; ++s) {
    ldsD[s * 256 + tid] = 1e30f;
    ldsI[s * 256 + tid] = 0x7fffffff;
  }
  float worst = 1e30f;

  for (int t = 0; t < NT; ++t) {
    int m0 = mbase + t * 64;
    // write staged B tile
#pragma unroll
    for (int i = 0; i < 4; ++i)
      Bs4[(ty + 16 * i) * 17 + tx] = pre[i];
    if (tid < 64) xxs[tid] = prex;
    // prefetch next tile (hidden under compute)
    if (t + 1 < NT) {
      int m1 = m0 + 64;
#pragma unroll
      for (int i = 0; i < 4; ++i)
        pre[i] = *(const float4*)&Xb[(size_t)(m1 + ty + 16 * i) * 64 + tx * 4];
      prex = XXb[m1 + lane];
    }
    __syncthreads();
    // GEMM: acc[mm] = dot(x_row(lane), x_m(w16+mm)); B reads wave-uniform
    float acc[16];
#pragma unroll
    for (int mm = 0; mm < 16; ++mm) {
      const float4* brow = &Bs4[(w16 + mm) * 17];
      float s = 0.f;
#pragma unroll
      for (int kb = 0; kb < 16; ++kb) {
        float4 b4 = brow[kb];
        s += areg[kb].x * b4.x;
        s += areg[kb].y * b4.y;
        s += areg[kb].z * b4.z;
        s += areg[kb].w * b4.w;
      }
      acc[mm] = s;
    }
    // select: d = xx[m] - 2*dot; quad gate + LDS-list sorted insert
#pragma unroll
    for (int q = 0; q < 4; ++q) {
      const float4 xq = *(const float4*)&xxs[w16 + 4 * q];
      float dv0 = fmaf(-2.f, acc[4 * q + 0], xq.x);
      float dv1 = fmaf(-2.f, acc[4 * q + 1], xq.y);
      float dv2 = fmaf(-2.f, acc[4 * q + 2], xq.z);
      float dv3 = fmaf(-2.f, acc[4 * q + 3], xq.w);
      float mn = fminf(fminf(dv0, dv1), fminf(dv2, dv3));
      if (mn < worst) {
        int gib = m0 + w16 + 4 * q;
#pragma unroll
        for (int j = 0; j < 4; ++j) {
          float d = (j == 0) ? dv0 : (j == 1) ? dv1 : (j == 2) ? dv2 : dv3;
          if (d < worst) {  // strict: tie keeps earlier (smaller gi)
            int s = KN - 1;
            while (s > 0) {
              float up = ldsD[(s - 1) * 256 + tid];
              if (up <= d) break;
              ldsD[s * 256 + tid] = up;
              ldsI[s * 256 + tid] = ldsI[(s - 1) * 256 + tid];
              --s;
            }
            ldsD[s * 256 + tid] = d;
            ldsI[s * 256 + tid] = gib + j;
            worst = ldsD[(KN - 1) * 256 + tid];
          }
        }
      }
    }
    __syncthreads();  // lists/Bs stable before next staging
  }
  // merge the 4 per-wave lists for each row (thread r handles row r)
  if (tid < 64) {
    int r = tid;
    int p0 = 0, p1 = 0, p2 = 0, p3 = 0;
    size_t pg = (size_t)b * NPTS + q0 + r;
    float* oD = outD + ((size_t)split * PTS_TOTAL + pg) * KN;
    int* oI = outI + ((size_t)split * PTS_TOTAL + pg) * KN;
    for (int rr = 0; rr < KN; ++rr) {
      float d0 = ldsD[p0 * 256 + r],       d1 = ldsD[p1 * 256 + 64 + r];
      float d2 = ldsD[p2 * 256 + 128 + r], d3 = ldsD[p3 * 256 + 192 + r];
      int i0 = ldsI[p0 * 256 + r],         i1 = ldsI[p1 * 256 + 64 + r];
      int i2 = ldsI[p2 * 256 + 128 + r],   i3 = ldsI[p3 * 256 + 192 + r];
      int sel = 0; float bdd = d0; int bii = i0;
      if (d1 < bdd || (d1 == bdd && i1 < bii)) { sel = 1; bdd = d1; bii = i1; }
      if (d2 < bdd || (d2 == bdd && i2 < bii)) { sel = 2; bdd = d2; bii = i2; }
      if (d3 < bdd || (d3 == bdd && i3 < bii)) { sel = 3; bdd = d3; bii = i3; }
      oD[rr] = bdd; oI[rr] = bii;
      if (sel == 0) ++p0; else if (sel == 1) ++p1; else if (sel == 2) ++p2; else ++p3;
    }
  }
}

// ---------------------------------------------------------------- merge 2 split lists
template<int KN>
__global__ void merge_splits_kernel(const float* __restrict__ D, const int* __restrict__ I,
                                    int* __restrict__ IDX) {
  int p = blockIdx.x * 256 + threadIdx.x;
  const float* d0 = D + (size_t)p * KN;
  const float* d1 = D + ((size_t)PTS_TOTAL + p) * KN;
  const int* i0 = I + (size_t)p * KN;
  const int* i1 = I + ((size_t)PTS_TOTAL + p) * KN;
  int* op = IDX + (size_t)p * KN;
  int a = 0, c = 0;
#pragma unroll
  for (int r = 0; r < KN; ++r) {
    float da = d0[a], dc = d1[c];
    int ia = i0[a], ic = i1[c];
    bool t = (dc < da) || (dc == da && ic < ia);
    op[r] = t ? ic : ia;
    if (t) ++c; else ++a;
  }
}

// ---------------------------------------------------------------- EC1: gather + MLP2 + max
__global__ __launch_bounds__(256) void ec1_kernel(
    const float* __restrict__ UV,   // [P][512] (u | v+b1)
    const int* __restrict__ IDX,    // [P][12]
    const float* __restrict__ W2T,  // [256 c][256 o]
    const float* __restrict__ B2,   // [256]
    float* __restrict__ OUT) {      // [P][256]
  __shared__ __align__(16) float h1[4][12][256];
  int wave = threadIdx.x >> 6;
  int lane = threadIdx.x & 63;
  int p = blockIdx.x * 4 + wave;
  int bbase = (p >> 12) << 12;  // batch start point
  const float* uvb = UV + (size_t)bbase * 512;
  const float* vrow = UV + (size_t)p * 512 + 256;
  float4 v4 = *(const float4*)&vrow[lane * 4];
#pragma unroll
  for (int k = 0; k < 12; ++k) {
    int jn = IDX[p * 12 + k];
    const float* urow = uvb + (size_t)jn * 512;
    float4 u4 = *(const float4*)&urow[lane * 4];
    float4 h;
    h.x = fmaxf(u4.x + v4.x, 0.f); h.y = fmaxf(u4.y + v4.y, 0.f);
    h.z = fmaxf(u4.z + v4.z, 0.f); h.w = fmaxf(u4.w + v4.w, 0.f);
    *(float4*)&h1[wave][k][lane * 4] = h;
  }
  __syncthreads();
  float acc[12][4] = {};
  const float* wbase = W2T + lane * 4;
  for (int c0 = 0; c0 < 256; c0 += 4) {
    float4 w0 = *(const float4*)&wbase[(size_t)(c0 + 0) * 256];
    float4 w1 = *(const float4*)&wbase[(size_t)(c0 + 1) * 256];
    float4 w2 = *(const float4*)&wbase[(size_t)(c0 + 2) * 256];
    float4 w3 = *(const float4*)&wbase[(size_t)(c0 + 3) * 256];
#pragma unroll
    for (int k = 0; k < 12; ++k) {
      float4 h = *(const float4*)&h1[wave][k][c0];  // wave-uniform broadcast
      acc[k][0] += h.x * w0.x + h.y * w1.x + h.z * w2.x + h.w * w3.x;
      acc[k][1] += h.x * w0.y + h.y * w1.y + h.z * w2.y + h.w * w3.y;
      acc[k][2] += h.x * w0.z + h.y * w1.z + h.z * w2.z + h.w * w3.z;
      acc[k][3] += h.x * w0.w + h.y * w1.w + h.z * w2.w + h.w * w3.w;
    }
  }
  float4 b4 = *(const float4*)&B2[lane * 4];
  float m0v = acc[0][0], m1v = acc[0][1], m2v = acc[0][2], m3v = acc[0][3];
#pragma unroll
  for (int k = 1; k < 12; ++k) {
    m0v = fmaxf(m0v, acc[k][0]); m1v = fmaxf(m1v, acc[k][1]);
    m2v = fmaxf(m2v, acc[k][2]); m3v = fmaxf(m3v, acc[k][3]);
  }
  float4 o4;
  o4.x = fmaxf(m0v + b4.x, 0.f); o4.y = fmaxf(m1v + b4.y, 0.f);
  o4.z = fmaxf(m2v + b4.z, 0.f); o4.w = fmaxf(m3v + b4.w, 0.f);
  *(float4*)&OUT[(size_t)p * 256 + lane * 4] = o4;
}

// ---------------------------------------------------------------- EC2: gather + relu + sum
__global__ __launch_bounds__(256) void ec2_kernel(
    const float* __restrict__ UV, const int* __restrict__ IDX,
    float* __restrict__ OUT) {
  int wave = threadIdx.x >> 6;
  int lane = threadIdx.x & 63;
  int p = blockIdx.x * 4 + wave;
  int bbase = (p >> 12) << 12;
  const float* uvb = UV + (size_t)bbase * 512;
  const float* vrow = UV + (size_t)p * 512 + 256;
  float4 v4 = *(const float4*)&vrow[lane * 4];
  float4 a4 = {0.f, 0.f, 0.f, 0.f};
#pragma unroll
  for (int k = 0; k < 8; ++k) {
    int jn = IDX[p * 8 + k];
    const float* urow = uvb + (size_t)jn * 512;
    float4 u4 = *(const float4*)&urow[lane * 4];
    a4.x += fmaxf(u4.x + v4.x, 0.f); a4.y += fmaxf(u4.y + v4.y, 0.f);
    a4.z += fmaxf(u4.z + v4.z, 0.f); a4.w += fmaxf(u4.w + v4.w, 0.f);
  }
  *(float4*)&OUT[(size_t)p * 256 + lane * 4] = a4;
}

// ---------------------------------------------------------------- final 64->1
__global__ void final_kernel(const float* __restrict__ X, const float* __restrict__ W,
                             const float* __restrict__ Bb, float* __restrict__ OUT) {
  int p = blockIdx.x * 4 + (threadIdx.x >> 6);
  int lane = threadIdx.x & 63;
  float v = X[(size_t)p * 64 + lane] * W[lane];
#pragma unroll
  for (int off = 32; off >= 1; off >>= 1) v += __shfl_xor(v, off);
  if (lane == 0) OUT[p] = fmaxf(v + Bb[0], 0.f);
}

// ---------------------------------------------------------------- launch
extern "C" void kernel_launch(void* const* d_in, const int* in_sizes, int n_in,
                              void* d_out, int out_size, void* d_ws, size_t ws_size,
                              hipStream_t stream) {
  const float* feature = (const float*)d_in[0];
  const float* conv0_w = (const float*)d_in[1];
  const float* conv0_b = (const float*)d_in[2];
  const float* ec1_w1  = (const float*)d_in[3];
  const float* ec1_b1  = (const float*)d_in[4];
  const float* ec1_w2  = (const float*)d_in[5];
  const float* ec1_b2  = (const float*)d_in[6];
  const float* conv1_w = (const float*)d_in[7];
  const float* conv1_b = (const float*)d_in[8];
  const float* ec2_w   = (const float*)d_in[9];
  const float* ec2_b   = (const float*)d_in[10];
  const float* dec1_w  = (const float*)d_in[11];
  const float* dec1_b  = (const float*)d_in[12];
  const float* dec2_w  = (const float*)d_in[13];
  const float* dec2_b  = (const float*)d_in[14];
  const float* out_w   = (const float*)d_in[15];
  const float* out_b   = (const float*)d_in[16];
  float* out = (float*)d_out;

  char* ws = (char*)d_ws;
  float* wuv1 = (float*)(ws + 0);
  float* buv1 = (float*)(ws + 131072);
  float* wuv2 = (float*)(ws + 133120);
  float* buv2 = (float*)(ws + 264192);
  float* w2t  = (float*)(ws + 266240);
  float* xx   = (float*)(ws + 528384);
  int*   idx  = (int*)  (ws + 659456);
  float* x0   = (float*)(ws + 2232320);   // x0 -> x1c -> xd2
  float* uv   = (float*)(ws + 10620928);  // knnD/knnI -> uv1 -> knnD/knnI -> uv2 -> xd1
  float* x1   = (float*)(ws + 77729792);  // x1 -> x2

  // knn scratch lives inside the (currently dead) uv region
  float* knnD = (float*)(ws + 10620928);
  int*   knnI = (int*)(ws + 10620928 + 3145728);

  const int P = PTS_TOTAL;

  prep_kernel<<<256, 256, 0, stream>>>(ec1_w1, ec1_b1, ec1_w2, ec2_w, ec2_b,
                                       wuv1, buv1, wuv2, buv2, w2t);
  gemm_rowmajor<true><<<dim3(P / 64, 1), 256, 0, stream>>>(feature, conv0_w, conv0_b, x0, P, 256, 64);
  sqnorm64<<<P / 4, 256, 0, stream>>>(x0, xx);
  knn_kernel<12><<<dim3(NPTS / 64, 2, NBATCH), 256, 0, stream>>>(x0, xx, knnD, knnI);
  merge_splits_kernel<12><<<P / 256, 256, 0, stream>>>(knnD, knnI, idx);
  gemm_rowmajor<false><<<dim3(P / 64, 8), 256, 0, stream>>>(x0, wuv1, buv1, uv, P, 64, 512);
  ec1_kernel<<<P / 4, 256, 0, stream>>>(uv, idx, w2t, ec1_b2, x1);
  gemm_rowmajor<true><<<dim3(P / 64, 1), 256, 0, stream>>>(x1, conv1_w, conv1_b, x0, P, 256, 64);
  sqnorm64<<<P / 4, 256, 0, stream>>>(x0, xx);
  knn_kernel<8><<<dim3(NPTS / 64, 2, NBATCH), 256, 0, stream>>>(x0, xx, knnD, knnI);
  merge_splits_kernel<8><<<P / 256, 256, 0, stream>>>(knnD, knnI, idx);
  gemm_rowmajor<false><<<dim3(P / 64, 8), 256, 0, stream>>>(x0, wuv2, buv2, uv, P, 64, 512);
  ec2_kernel<<<P / 4, 256, 0, stream>>>(uv, idx, x1);
  float* xd1 = uv;
  gemm_rowmajor<true><<<dim3(P / 64, 2), 256, 0, stream>>>(x1, dec1_w, dec1_b, xd1, P, 256, 128);
  float* xd2 = x0;
  gemm_rowmajor<true><<<dim3(P / 64, 1), 256, 0, stream>>>(xd1, dec2_w, dec2_b, xd2, P, 128, 64);
  final_kernel<<<P / 4, 256, 0, stream>>>(xd2, out_w, out_b, out);
}

// Round 9
// 1755.651 us; speedup vs baseline: 12.1248x; 12.1248x over previous
//
#include <hip/hip_runtime.h>
#include <hip/hip_bf16.h>

// Problem: B=8, N=4096, C=256, c4=64. All fp32. P = B*N = 32768 points.
//
//  x0  = relu(feature @ conv0_w^T + b)            [P,64]
//  idx1 = knn12(x0);  EC1: h1=relu(u1[j]+v1[i]), h2=relu(h1@W2^T+b2), max_k -> x1 [P,256]
//  x1c = relu(x1 @ conv1_w^T + b)                 [P,64]
//  idx2 = knn8(x1c);  EC2: x2 = sum_k relu(u2[j]+v2[i])  [P,256]
//  decoder: 256->128->64->1 (all relu)
//
// u/v decomposition: W=[A|B]: edge(o) = x_j.A[o] + x_i.(B[o]-A[o]) = u[j][o] + v[i][o]

#define PTS_TOTAL 32768
#define NPTS 4096
#define NBATCH 8

// ---------------------------------------------------------------- prep weights
__global__ void prep_kernel(const float* __restrict__ w1, const float* __restrict__ b1,
                            const float* __restrict__ w2,
                            const float* __restrict__ ew, const float* __restrict__ eb,
                            float* __restrict__ wuv1, float* __restrict__ buv1,
                            float* __restrict__ wuv2, float* __restrict__ buv2,
                            float* __restrict__ w2t) {
  int tid = blockIdx.x * 256 + threadIdx.x;
  if (tid < 512 * 64) {
    int o = tid / 64, c = tid % 64;
    int orow = o & 255;
    float a  = w1[orow * 128 + c];
    float bb = w1[orow * 128 + 64 + c];
    wuv1[tid] = (o < 256) ? a : (bb - a);
    float a2  = ew[orow * 128 + c];
    float b2p = ew[orow * 128 + 64 + c];
    wuv2[tid] = (o < 256) ? a2 : (b2p - a2);
  }
  if (tid < 512) {
    buv1[tid] = (tid < 256) ? 0.f : b1[tid - 256];
    buv2[tid] = (tid < 256) ? 0.f : eb[tid - 256];
  }
  if (tid < 65536) {
    int o = tid / 256, c = tid % 256;
    w2t[c * 256 + o] = w2[o * 256 + c];
  }
}

// ---------------------------------------------------------------- generic fp32 GEMM
template<bool RELU>
__global__ __launch_bounds__(256) void gemm_rowmajor(
    const float* __restrict__ A, const float* __restrict__ W,
    const float* __restrict__ bias, float* __restrict__ Cmat,
    int M, int K, int Cout) {
  __shared__ __align__(16) float As[32][68];
  __shared__ __align__(16) float Bs[32][68];
  int m0 = blockIdx.x * 64;
  int n0 = blockIdx.y * 64;
  int tid = threadIdx.x;
  int tx = tid & 15, ty = tid >> 4;
  float acc[4][4] = {};
  for (int k0 = 0; k0 < K; k0 += 32) {
#pragma unroll
    for (int i = 0; i < 2; ++i) {
      int rr = (tid >> 3) + 32 * i;
      int cc = (tid & 7) * 4;
      float4 va = *(const float4*)&A[(size_t)(m0 + rr) * K + k0 + cc];
      float4 vb = *(const float4*)&W[(size_t)(n0 + rr) * K + k0 + cc];
      As[cc + 0][rr] = va.x; As[cc + 1][rr] = va.y; As[cc + 2][rr] = va.z; As[cc + 3][rr] = va.w;
      Bs[cc + 0][rr] = vb.x; Bs[cc + 1][rr] = vb.y; Bs[cc + 2][rr] = vb.z; Bs[cc + 3][rr] = vb.w;
    }
    __syncthreads();
#pragma unroll 8
    for (int k = 0; k < 32; ++k) {
      float4 a4 = *(const float4*)&As[k][ty * 4];
      float4 b4 = *(const float4*)&Bs[k][tx * 4];
      float a[4] = {a4.x, a4.y, a4.z, a4.w};
      float b[4] = {b4.x, b4.y, b4.z, b4.w};
#pragma unroll
      for (int ii = 0; ii < 4; ++ii)
#pragma unroll
        for (int jj = 0; jj < 4; ++jj)
          acc[ii][jj] += a[ii] * b[jj];
    }
    __syncthreads();
  }
  float4 bias4 = *(const float4*)&bias[n0 + tx * 4];
  float bv[4] = {bias4.x, bias4.y, bias4.z, bias4.w};
#pragma unroll
  for (int ii = 0; ii < 4; ++ii) {
    int m = m0 + ty * 4 + ii;
    float4 v4;
    float* vp = (float*)&v4;
#pragma unroll
    for (int jj = 0; jj < 4; ++jj) {
      float v = acc[ii][jj] + bv[jj];
      if (RELU) v = fmaxf(v, 0.f);
      vp[jj] = v;
    }
    *(float4*)&Cmat[(size_t)m * Cout + n0 + tx * 4] = v4;
  }
}

// ---------------------------------------------------------------- squared norms (C=64)
__global__ void sqnorm64(const float* __restrict__ X, float* __restrict__ xx) {
  int p = blockIdx.x * 4 + (threadIdx.x >> 6);
  int lane = threadIdx.x & 63;
  float v = X[(size_t)p * 64 + lane];
  float s = v * v;
#pragma unroll
  for (int off = 32; off >= 1; off >>= 1) s += __shfl_xor(s, off);
  if (lane == 0) xx[p] = s;
}

// ---------------------------------------------------------------- knn v8
// = r2's proven 4x4 register-tiled GEMM (VGPR=120, no spill) + r6's proven
// named-scalar gated insert (88% VALUBusy) + conflict-free Dbuf transpose.
// Mapping fix vs r2: select uses ssel = WAVE index (tid>>6), row = tid&63, so
// each b128 octet reads 8 distinct Dbuf rows (stride 17 f4 -> 8 distinct bank
// quads, conflict-free); r2's (tid>>2, tid&3) map had 2 addrs/quad per octet.
// splits=1: 512 blocks = 2/CU exact; knn writes IDX directly (no merge pass).
#define ORD(a, b)                                                   \
  { bool sw_ = td##b < td##a;                                       \
    float lo_ = fminf(td##a, td##b), hi_ = fmaxf(td##a, td##b);     \
    int il_ = sw_ ? ti##b : ti##a, ih_ = sw_ ? ti##a : ti##b;       \
    td##a = lo_; td##b = hi_; ti##a = il_; ti##b = ih_; }

#define INS(d, gi)                                                  \
  if (KN == 12) {                                                   \
    if ((d) < td11) {                                               \
      td11 = (d); ti11 = (gi);                                      \
      ORD(10,11) ORD(9,10) ORD(8,9) ORD(7,8) ORD(6,7) ORD(5,6)      \
      ORD(4,5) ORD(3,4) ORD(2,3) ORD(1,2) ORD(0,1)                  \
    }                                                               \
  } else {                                                          \
    if ((d) < td7) {                                                \
      td7 = (d); ti7 = (gi);                                        \
      ORD(6,7) ORD(5,6) ORD(4,5) ORD(3,4) ORD(2,3) ORD(1,2) ORD(0,1)\
    }                                                               \
  }

template<int KN>
__global__ __launch_bounds__(256) void knn_kernel(
    const float* __restrict__ X,   // [B][N][64]
    const float* __restrict__ XX,  // [B][N]
    int* __restrict__ IDX) {       // [B][N][KN]
  __shared__ __align__(16) float As[64][68];    // [c][q]
  __shared__ __align__(16) float Bs[64][68];    // [c][m]
  __shared__ __align__(16) float Dbuf[64][68];  // [q][m] distances
  __shared__ float xxs[64];
  int tid = threadIdx.x;
  int tx = tid & 15, ty = tid >> 4;   // GEMM / staging map
  int row = tid & 63, ssel = tid >> 6;  // select map (ssel = wave idx)
  int b = blockIdx.y;
  int q0 = blockIdx.x * 64;
  const int NT = NPTS / 64;
  const float* Xb = X + (size_t)b * NPTS * 64;
  const float* XXb = XX + (size_t)b * NPTS;
  // stage A once: transposed scalar writes (once per kernel, conflicts ok)
#pragma unroll
  for (int i = 0; i < 4; ++i) {
    float4 v = *(const float4*)&Xb[(size_t)(q0 + ty + 16 * i) * 64 + tx * 4];
    As[tx * 4 + 0][ty + 16 * i] = v.x; As[tx * 4 + 1][ty + 16 * i] = v.y;
    As[tx * 4 + 2][ty + 16 * i] = v.z; As[tx * 4 + 3][ty + 16 * i] = v.w;
  }
  // top-K list: named scalar registers (r6 form)
  float td0 = 1e30f, td1 = 1e30f, td2 = 1e30f, td3 = 1e30f,
        td4 = 1e30f, td5 = 1e30f, td6 = 1e30f, td7 = 1e30f,
        td8 = 1e30f, td9 = 1e30f, td10 = 1e30f, td11 = 1e30f;
  int ti0 = 0x7fffffff, ti1 = 0x7fffffff, ti2 = 0x7fffffff, ti3 = 0x7fffffff,
      ti4 = 0x7fffffff, ti5 = 0x7fffffff, ti6 = 0x7fffffff, ti7 = 0x7fffffff,
      ti8 = 0x7fffffff, ti9 = 0x7fffffff, ti10 = 0x7fffffff, ti11 = 0x7fffffff;
  // prefetch B tile 0
  float4 pre[4];
  float prex;
#pragma unroll
  for (int i = 0; i < 4; ++i)
    pre[i] = *(const float4*)&Xb[(size_t)(ty + 16 * i) * 64 + tx * 4];
  prex = XXb[tid & 63];

  for (int t = 0; t < NT; ++t) {
    int m0 = t * 64;
    // write staged B tile (transposed scalar)
#pragma unroll
    for (int i = 0; i < 4; ++i) {
      Bs[tx * 4 + 0][ty + 16 * i] = pre[i].x; Bs[tx * 4 + 1][ty + 16 * i] = pre[i].y;
      Bs[tx * 4 + 2][ty + 16 * i] = pre[i].z; Bs[tx * 4 + 3][ty + 16 * i] = pre[i].w;
    }
    if (tid < 64) xxs[tid] = prex;
    // prefetch next tile (hidden under GEMM+select)
    if (t + 1 < NT) {
      int m1 = m0 + 64;
#pragma unroll
      for (int i = 0; i < 4; ++i)
        pre[i] = *(const float4*)&Xb[(size_t)(m1 + ty + 16 * i) * 64 + tx * 4];
      prex = XXb[m1 + (tid & 63)];
    }
    __syncthreads();
    // GEMM 4x4: rows ty*4+ii, cols tx*4+jj
    float acc[4][4] = {};
#pragma unroll 8
    for (int k = 0; k < 64; ++k) {
      float4 a4 = *(const float4*)&As[k][ty * 4];
      float4 b4 = *(const float4*)&Bs[k][tx * 4];
      float a[4] = {a4.x, a4.y, a4.z, a4.w};
      float bb[4] = {b4.x, b4.y, b4.z, b4.w};
#pragma unroll
      for (int ii = 0; ii < 4; ++ii)
#pragma unroll
        for (int jj = 0; jj < 4; ++jj)
          acc[ii][jj] += a[ii] * bb[jj];
    }
    // fold d = xx[m] - 2*dot at write; f4 writes, stride 17 f4 (conflict-free)
    float4 xx4 = *(const float4*)&xxs[tx * 4];
    float xv[4] = {xx4.x, xx4.y, xx4.z, xx4.w};
#pragma unroll
    for (int ii = 0; ii < 4; ++ii) {
      float4 d4;
      float* dp = (float*)&d4;
#pragma unroll
      for (int jj = 0; jj < 4; ++jj) dp[jj] = fmaf(-2.f, acc[ii][jj], xv[jj]);
      *(float4*)&Dbuf[ty * 4 + ii][tx * 4] = d4;
    }
    __syncthreads();
    // select: thread (row, ssel) scans its row's 16 m (4 f4 reads, conflict-free)
#pragma unroll
    for (int qq = 0; qq < 4; ++qq) {
      float4 d4 = *(const float4*)&Dbuf[row][ssel * 16 + qq * 4];
      float mn = fminf(fminf(d4.x, d4.y), fminf(d4.z, d4.w));
      float worst = (KN == 12) ? td11 : td7;
      if (mn < worst) {
        int gib = m0 + ssel * 16 + qq * 4;
        INS(d4.x, gib + 0)
        INS(d4.y, gib + 1)
        INS(d4.z, gib + 2)
        INS(d4.w, gib + 3)
      }
    }
    __syncthreads();  // selects done before next tile's staging/GEMM overwrite
  }
  // dump named lists; merge the 4 per-wave lists per row; write IDX directly
  const int S = 4 * KN + 1;
  float* cd = &As[0][0];   // 4352 floats >= 64*S
  int* ci = (int*)&Bs[0][0];
  {
    float* cdr = cd + row * S + ssel * KN;
    int* cir = ci + row * S + ssel * KN;
    cdr[0] = td0; cdr[1] = td1; cdr[2] = td2; cdr[3] = td3;
    cdr[4] = td4; cdr[5] = td5; cdr[6] = td6; cdr[7] = td7;
    cir[0] = ti0; cir[1] = ti1; cir[2] = ti2; cir[3] = ti3;
    cir[4] = ti4; cir[5] = ti5; cir[6] = ti6; cir[7] = ti7;
    if (KN == 12) {
      cdr[8] = td8; cdr[9] = td9; cdr[10] = td10; cdr[11] = td11;
      cir[8] = ti8; cir[9] = ti9; cir[10] = ti10; cir[11] = ti11;
    }
  }
  __syncthreads();
  if (tid < 64) {
    int r = tid;
    int p0 = 0, p1 = 0, p2 = 0, p3 = 0;
    const float* cdr = cd + r * S;
    const int* cir = ci + r * S;
    int* op = IDX + ((size_t)b * NPTS + q0 + r) * KN;
    for (int rr = 0; rr < KN; ++rr) {
      float d0 = cdr[0 * KN + p0], d1 = cdr[1 * KN + p1];
      float d2 = cdr[2 * KN + p2], d3 = cdr[3 * KN + p3];
      int i0 = cir[0 * KN + p0], i1 = cir[1 * KN + p1];
      int i2 = cir[2 * KN + p2], i3 = cir[3 * KN + p3];
      int sel = 0; float bdd = d0; int bii = i0;
      if (d1 < bdd || (d1 == bdd && i1 < bii)) { sel = 1; bdd = d1; bii = i1; }
      if (d2 < bdd || (d2 == bdd && i2 < bii)) { sel = 2; bdd = d2; bii = i2; }
      if (d3 < bdd || (d3 == bdd && i3 < bii)) { sel = 3; bdd = d3; bii = i3; }
      op[rr] = bii;
      if (sel == 0) ++p0; else if (sel == 1) ++p1; else if (sel == 2) ++p2; else ++p3;
    }
  }
}
#undef INS
#undef ORD

// ---------------------------------------------------------------- EC1: gather + MLP2 + max
__global__ __launch_bounds__(256) void ec1_kernel(
    const float* __restrict__ UV,   // [P][512] (u | v+b1)
    const int* __restrict__ IDX,    // [P][12]
    const float* __restrict__ W2T,  // [256 c][256 o]
    const float* __restrict__ B2,   // [256]
    float* __restrict__ OUT) {      // [P][256]
  __shared__ __align__(16) float h1[4][12][256];
  int wave = threadIdx.x >> 6;
  int lane = threadIdx.x & 63;
  int p = blockIdx.x * 4 + wave;
  int bbase = (p >> 12) << 12;  // batch start point
  const float* uvb = UV + (size_t)bbase * 512;
  const float* vrow = UV + (size_t)p * 512 + 256;
  float4 v4 = *(const float4*)&vrow[lane * 4];
#pragma unroll
  for (int k = 0; k < 12; ++k) {
    int jn = IDX[p * 12 + k];
    const float* urow = uvb + (size_t)jn * 512;
    float4 u4 = *(const float4*)&urow[lane * 4];
    float4 h;
    h.x = fmaxf(u4.x + v4.x, 0.f); h.y = fmaxf(u4.y + v4.y, 0.f);
    h.z = fmaxf(u4.z + v4.z, 0.f); h.w = fmaxf(u4.w + v4.w, 0.f);
    *(float4*)&h1[wave][k][lane * 4] = h;
  }
  __syncthreads();
  float acc[12][4] = {};
  const float* wbase = W2T + lane * 4;
  for (int c0 = 0; c0 < 256; c0 += 4) {
    float4 w0 = *(const float4*)&wbase[(size_t)(c0 + 0) * 256];
    float4 w1 = *(const float4*)&wbase[(size_t)(c0 + 1) * 256];
    float4 w2 = *(const float4*)&wbase[(size_t)(c0 + 2) * 256];
    float4 w3 = *(const float4*)&wbase[(size_t)(c0 + 3) * 256];
#pragma unroll
    for (int k = 0; k < 12; ++k) {
      float4 h = *(const float4*)&h1[wave][k][c0];  // wave-uniform broadcast
      acc[k][0] += h.x * w0.x + h.y * w1.x + h.z * w2.x + h.w * w3.x;
      acc[k][1] += h.x * w0.y + h.y * w1.y + h.z * w2.y + h.w * w3.y;
      acc[k][2] += h.x * w0.z + h.y * w1.z + h.z * w2.z + h.w * w3.z;
      acc[k][3] += h.x * w0.w + h.y * w1.w + h.z * w2.w + h.w * w3.w;
    }
  }
  float4 b4 = *(const float4*)&B2[lane * 4];
  float m0v = acc[0][0], m1v = acc[0][1], m2v = acc[0][2], m3v = acc[0][3];
#pragma unroll
  for (int k = 1; k < 12; ++k) {
    m0v = fmaxf(m0v, acc[k][0]); m1v = fmaxf(m1v, acc[k][1]);
    m2v = fmaxf(m2v, acc[k][2]); m3v = fmaxf(m3v, acc[k][3]);
  }
  float4 o4;
  o4.x = fmaxf(m0v + b4.x, 0.f); o4.y = fmaxf(m1v + b4.y, 0.f);
  o4.z = fmaxf(m2v + b4.z, 0.f); o4.w = fmaxf(m3v + b4.w, 0.f);
  *(float4*)&OUT[(size_t)p * 256 + lane * 4] = o4;
}

// ---------------------------------------------------------------- EC2: gather + relu + sum
__global__ __launch_bounds__(256) void ec2_kernel(
    const float* __restrict__ UV, const int* __restrict__ IDX,
    float* __restrict__ OUT) {
  int wave = threadIdx.x >> 6;
  int lane = threadIdx.x & 63;
  int p = blockIdx.x * 4 + wave;
  int bbase = (p >> 12) << 12;
  const float* uvb = UV + (size_t)bbase * 512;
  const float* vrow = UV + (size_t)p * 512 + 256;
  float4 v4 = *(const float4*)&vrow[lane * 4];
  float4 a4 = {0.f, 0.f, 0.f, 0.f};
#pragma unroll
  for (int k = 0; k < 8; ++k) {
    int jn = IDX[p * 8 + k];
    const float* urow = uvb + (size_t)jn * 512;
    float4 u4 = *(const float4*)&urow[lane * 4];
    a4.x += fmaxf(u4.x + v4.x, 0.f); a4.y += fmaxf(u4.y + v4.y, 0.f);
    a4.z += fmaxf(u4.z + v4.z, 0.f); a4.w += fmaxf(u4.w + v4.w, 0.f);
  }
  *(float4*)&OUT[(size_t)p * 256 + lane * 4] = a4;
}

// ---------------------------------------------------------------- final 64->1
__global__ void final_kernel(const float* __restrict__ X, const float* __restrict__ W,
                             const float* __restrict__ Bb, float* __restrict__ OUT) {
  int p = blockIdx.x * 4 + (threadIdx.x >> 6);
  int lane = threadIdx.x & 63;
  float v = X[(size_t)p * 64 + lane] * W[lane];
#pragma unroll
  for (int off = 32; off >= 1; off >>= 1) v += __shfl_xor(v, off);
  if (lane == 0) OUT[p] = fmaxf(v + Bb[0], 0.f);
}

// ---------------------------------------------------------------- launch
extern "C" void kernel_launch(void* const* d_in, const int* in_sizes, int n_in,
                              void* d_out, int out_size, void* d_ws, size_t ws_size,
                              hipStream_t stream) {
  const float* feature = (const float*)d_in[0];
  const float* conv0_w = (const float*)d_in[1];
  const float* conv0_b = (const float*)d_in[2];
  const float* ec1_w1  = (const float*)d_in[3];
  const float* ec1_b1  = (const float*)d_in[4];
  const float* ec1_w2  = (const float*)d_in[5];
  const float* ec1_b2  = (const float*)d_in[6];
  const float* conv1_w = (const float*)d_in[7];
  const float* conv1_b = (const float*)d_in[8];
  const float* ec2_w   = (const float*)d_in[9];
  const float* ec2_b   = (const float*)d_in[10];
  const float* dec1_w  = (const float*)d_in[11];
  const float* dec1_b  = (const float*)d_in[12];
  const float* dec2_w  = (const float*)d_in[13];
  const float* dec2_b  = (const float*)d_in[14];
  const float* out_w   = (const float*)d_in[15];
  const float* out_b   = (const float*)d_in[16];
  float* out = (float*)d_out;

  char* ws = (char*)d_ws;
  float* wuv1 = (float*)(ws + 0);
  float* buv1 = (float*)(ws + 131072);
  float* wuv2 = (float*)(ws + 133120);
  float* buv2 = (float*)(ws + 264192);
  float* w2t  = (float*)(ws + 266240);
  float* xx   = (float*)(ws + 528384);
  int*   idx  = (int*)  (ws + 659456);
  float* x0   = (float*)(ws + 2232320);   // x0 -> x1c -> xd2
  float* uv   = (float*)(ws + 10620928);  // uv1 -> uv2 -> xd1
  float* x1   = (float*)(ws + 77729792);  // x1 -> x2

  const int P = PTS_TOTAL;

  prep_kernel<<<256, 256, 0, stream>>>(ec1_w1, ec1_b1, ec1_w2, ec2_w, ec2_b,
                                       wuv1, buv1, wuv2, buv2, w2t);
  gemm_rowmajor<true><<<dim3(P / 64, 1), 256, 0, stream>>>(feature, conv0_w, conv0_b, x0, P, 256, 64);
  sqnorm64<<<P / 4, 256, 0, stream>>>(x0, xx);
  knn_kernel<12><<<dim3(NPTS / 64, NBATCH), 256, 0, stream>>>(x0, xx, idx);
  gemm_rowmajor<false><<<dim3(P / 64, 8), 256, 0, stream>>>(x0, wuv1, buv1, uv, P, 64, 512);
  ec1_kernel<<<P / 4, 256, 0, stream>>>(uv, idx, w2t, ec1_b2, x1);
  gemm_rowmajor<true><<<dim3(P / 64, 1), 256, 0, stream>>>(x1, conv1_w, conv1_b, x0, P, 256, 64);
  sqnorm64<<<P / 4, 256, 0, stream>>>(x0, xx);
  knn_kernel<8><<<dim3(NPTS / 64, NBATCH), 256, 0, stream>>>(x0, xx, idx);
  gemm_rowmajor<false><<<dim3(P / 64, 8), 256, 0, stream>>>(x0, wuv2, buv2, uv, P, 64, 512);
  ec2_kernel<<<P / 4, 256, 0, stream>>>(uv, idx, x1);
  float* xd1 = uv;
  gemm_rowmajor<true><<<dim3(P / 64, 2), 256, 0, stream>>>(x1, dec1_w, dec1_b, xd1, P, 256, 128);
  float* xd2 = x0;
  gemm_rowmajor<true><<<dim3(P / 64, 1), 256, 0, stream>>>(xd1, dec2_w, dec2_b, xd2, P, 128, 64);
  final_kernel<<<P / 4, 256, 0, stream>>>(xd2, out_w, out_b, out);
}

// Round 10
// 1682.576 us; speedup vs baseline: 12.6514x; 1.0434x over previous
//
#include <hip/hip_runtime.h>
#include <hip/hip_bf16.h>

// Problem: B=8, N=4096, C=256, c4=64. All fp32. P = B*N = 32768 points.
//
//  x0  = relu(feature @ conv0_w^T + b)            [P,64]
//  idx1 = knn12(x0);  EC1: h1=relu(u1[j]+v1[i]), h2=relu(h1@W2^T+b2), max_k -> x1 [P,256]
//  x1c = relu(x1 @ conv1_w^T + b)                 [P,64]
//  idx2 = knn8(x1c);  EC2: x2 = sum_k relu(u2[j]+v2[i])  [P,256]
//  decoder: 256->128->64->1 (all relu)
//
// u/v decomposition: W=[A|B]: edge(o) = x_j.A[o] + x_i.(B[o]-A[o]) = u[j][o] + v[i][o]

#define PTS_TOTAL 32768
#define NPTS 4096
#define NBATCH 8

// ---------------------------------------------------------------- prep weights
__global__ void prep_kernel(const float* __restrict__ w1, const float* __restrict__ b1,
                            const float* __restrict__ w2,
                            const float* __restrict__ ew, const float* __restrict__ eb,
                            float* __restrict__ wuv1, float* __restrict__ buv1,
                            float* __restrict__ wuv2, float* __restrict__ buv2,
                            float* __restrict__ w2t) {
  int tid = blockIdx.x * 256 + threadIdx.x;
  if (tid < 512 * 64) {
    int o = tid / 64, c = tid % 64;
    int orow = o & 255;
    float a  = w1[orow * 128 + c];
    float bb = w1[orow * 128 + 64 + c];
    wuv1[tid] = (o < 256) ? a : (bb - a);
    float a2  = ew[orow * 128 + c];
    float b2p = ew[orow * 128 + 64 + c];
    wuv2[tid] = (o < 256) ? a2 : (b2p - a2);
  }
  if (tid < 512) {
    buv1[tid] = (tid < 256) ? 0.f : b1[tid - 256];
    buv2[tid] = (tid < 256) ? 0.f : eb[tid - 256];
  }
  if (tid < 65536) {
    int o = tid / 256, c = tid % 256;
    w2t[c * 256 + o] = w2[o * 256 + c];
  }
}

// ---------------------------------------------------------------- generic fp32 GEMM
template<bool RELU>
__global__ __launch_bounds__(256) void gemm_rowmajor(
    const float* __restrict__ A, const float* __restrict__ W,
    const float* __restrict__ bias, float* __restrict__ Cmat,
    int M, int K, int Cout) {
  __shared__ __align__(16) float As[32][68];
  __shared__ __align__(16) float Bs[32][68];
  int m0 = blockIdx.x * 64;
  int n0 = blockIdx.y * 64;
  int tid = threadIdx.x;
  int tx = tid & 15, ty = tid >> 4;
  float acc[4][4] = {};
  for (int k0 = 0; k0 < K; k0 += 32) {
#pragma unroll
    for (int i = 0; i < 2; ++i) {
      int rr = (tid >> 3) + 32 * i;
      int cc = (tid & 7) * 4;
      float4 va = *(const float4*)&A[(size_t)(m0 + rr) * K + k0 + cc];
      float4 vb = *(const float4*)&W[(size_t)(n0 + rr) * K + k0 + cc];
      As[cc + 0][rr] = va.x; As[cc + 1][rr] = va.y; As[cc + 2][rr] = va.z; As[cc + 3][rr] = va.w;
      Bs[cc + 0][rr] = vb.x; Bs[cc + 1][rr] = vb.y; Bs[cc + 2][rr] = vb.z; Bs[cc + 3][rr] = vb.w;
    }
    __syncthreads();
#pragma unroll 8
    for (int k = 0; k < 32; ++k) {
      float4 a4 = *(const float4*)&As[k][ty * 4];
      float4 b4 = *(const float4*)&Bs[k][tx * 4];
      float a[4] = {a4.x, a4.y, a4.z, a4.w};
      float b[4] = {b4.x, b4.y, b4.z, b4.w};
#pragma unroll
      for (int ii = 0; ii < 4; ++ii)
#pragma unroll
        for (int jj = 0; jj < 4; ++jj)
          acc[ii][jj] += a[ii] * b[jj];
    }
    __syncthreads();
  }
  float4 bias4 = *(const float4*)&bias[n0 + tx * 4];
  float bv[4] = {bias4.x, bias4.y, bias4.z, bias4.w};
#pragma unroll
  for (int ii = 0; ii < 4; ++ii) {
    int m = m0 + ty * 4 + ii;
    float4 v4;
    float* vp = (float*)&v4;
#pragma unroll
    for (int jj = 0; jj < 4; ++jj) {
      float v = acc[ii][jj] + bv[jj];
      if (RELU) v = fmaxf(v, 0.f);
      vp[jj] = v;
    }
    *(float4*)&Cmat[(size_t)m * Cout + n0 + tx * 4] = v4;
  }
}

// ---------------------------------------------------------------- squared norms (C=64)
__global__ void sqnorm64(const float* __restrict__ X, float* __restrict__ xx) {
  int p = blockIdx.x * 4 + (threadIdx.x >> 6);
  int lane = threadIdx.x & 63;
  float v = X[(size_t)p * 64 + lane];
  float s = v * v;
#pragma unroll
  for (int off = 32; off >= 1; off >>= 1) s += __shfl_xor(s, off);
  if (lane == 0) xx[p] = s;
}

// ---------------------------------------------------------------- knn v8 (unchanged from r9 — stable)
#define ORD(a, b)                                                   \
  { bool sw_ = td##b < td##a;                                       \
    float lo_ = fminf(td##a, td##b), hi_ = fmaxf(td##a, td##b);     \
    int il_ = sw_ ? ti##b : ti##a, ih_ = sw_ ? ti##a : ti##b;       \
    td##a = lo_; td##b = hi_; ti##a = il_; ti##b = ih_; }

#define INS(d, gi)                                                  \
  if (KN == 12) {                                                   \
    if ((d) < td11) {                                               \
      td11 = (d); ti11 = (gi);                                      \
      ORD(10,11) ORD(9,10) ORD(8,9) ORD(7,8) ORD(6,7) ORD(5,6)      \
      ORD(4,5) ORD(3,4) ORD(2,3) ORD(1,2) ORD(0,1)                  \
    }                                                               \
  } else {                                                          \
    if ((d) < td7) {                                                \
      td7 = (d); ti7 = (gi);                                        \
      ORD(6,7) ORD(5,6) ORD(4,5) ORD(3,4) ORD(2,3) ORD(1,2) ORD(0,1)\
    }                                                               \
  }

template<int KN>
__global__ __launch_bounds__(256) void knn_kernel(
    const float* __restrict__ X,   // [B][N][64]
    const float* __restrict__ XX,  // [B][N]
    int* __restrict__ IDX) {       // [B][N][KN]
  __shared__ __align__(16) float As[64][68];    // [c][q]
  __shared__ __align__(16) float Bs[64][68];    // [c][m]
  __shared__ __align__(16) float Dbuf[64][68];  // [q][m] distances
  __shared__ float xxs[64];
  int tid = threadIdx.x;
  int tx = tid & 15, ty = tid >> 4;   // GEMM / staging map
  int row = tid & 63, ssel = tid >> 6;  // select map (ssel = wave idx)
  int b = blockIdx.y;
  int q0 = blockIdx.x * 64;
  const int NT = NPTS / 64;
  const float* Xb = X + (size_t)b * NPTS * 64;
  const float* XXb = XX + (size_t)b * NPTS;
  // stage A once: transposed scalar writes (once per kernel, conflicts ok)
#pragma unroll
  for (int i = 0; i < 4; ++i) {
    float4 v = *(const float4*)&Xb[(size_t)(q0 + ty + 16 * i) * 64 + tx * 4];
    As[tx * 4 + 0][ty + 16 * i] = v.x; As[tx * 4 + 1][ty + 16 * i] = v.y;
    As[tx * 4 + 2][ty + 16 * i] = v.z; As[tx * 4 + 3][ty + 16 * i] = v.w;
  }
  // top-K list: named scalar registers (r6 form)
  float td0 = 1e30f, td1 = 1e30f, td2 = 1e30f, td3 = 1e30f,
        td4 = 1e30f, td5 = 1e30f, td6 = 1e30f, td7 = 1e30f,
        td8 = 1e30f, td9 = 1e30f, td10 = 1e30f, td11 = 1e30f;
  int ti0 = 0x7fffffff, ti1 = 0x7fffffff, ti2 = 0x7fffffff, ti3 = 0x7fffffff,
      ti4 = 0x7fffffff, ti5 = 0x7fffffff, ti6 = 0x7fffffff, ti7 = 0x7fffffff,
      ti8 = 0x7fffffff, ti9 = 0x7fffffff, ti10 = 0x7fffffff, ti11 = 0x7fffffff;
  // prefetch B tile 0
  float4 pre[4];
  float prex;
#pragma unroll
  for (int i = 0; i < 4; ++i)
    pre[i] = *(const float4*)&Xb[(size_t)(ty + 16 * i) * 64 + tx * 4];
  prex = XXb[tid & 63];

  for (int t = 0; t < NT; ++t) {
    int m0 = t * 64;
    // write staged B tile (transposed scalar)
#pragma unroll
    for (int i = 0; i < 4; ++i) {
      Bs[tx * 4 + 0][ty + 16 * i] = pre[i].x; Bs[tx * 4 + 1][ty + 16 * i] = pre[i].y;
      Bs[tx * 4 + 2][ty + 16 * i] = pre[i].z; Bs[tx * 4 + 3][ty + 16 * i] = pre[i].w;
    }
    if (tid < 64) xxs[tid] = prex;
    // prefetch next tile (hidden under GEMM+select)
    if (t + 1 < NT) {
      int m1 = m0 + 64;
#pragma unroll
      for (int i = 0; i < 4; ++i)
        pre[i] = *(const float4*)&Xb[(size_t)(m1 + ty + 16 * i) * 64 + tx * 4];
      prex = XXb[m1 + (tid & 63)];
    }
    __syncthreads();
    // GEMM 4x4: rows ty*4+ii, cols tx*4+jj
    float acc[4][4] = {};
#pragma unroll 8
    for (int k = 0; k < 64; ++k) {
      float4 a4 = *(const float4*)&As[k][ty * 4];
      float4 b4 = *(const float4*)&Bs[k][tx * 4];
      float a[4] = {a4.x, a4.y, a4.z, a4.w};
      float bb[4] = {b4.x, b4.y, b4.z, b4.w};
#pragma unroll
      for (int ii = 0; ii < 4; ++ii)
#pragma unroll
        for (int jj = 0; jj < 4; ++jj)
          acc[ii][jj] += a[ii] * bb[jj];
    }
    // fold d = xx[m] - 2*dot at write; f4 writes, stride 17 f4 (conflict-free)
    float4 xx4 = *(const float4*)&xxs[tx * 4];
    float xv[4] = {xx4.x, xx4.y, xx4.z, xx4.w};
#pragma unroll
    for (int ii = 0; ii < 4; ++ii) {
      float4 d4;
      float* dp = (float*)&d4;
#pragma unroll
      for (int jj = 0; jj < 4; ++jj) dp[jj] = fmaf(-2.f, acc[ii][jj], xv[jj]);
      *(float4*)&Dbuf[ty * 4 + ii][tx * 4] = d4;
    }
    __syncthreads();
    // select: thread (row, ssel) scans its row's 16 m (4 f4 reads, conflict-free)
#pragma unroll
    for (int qq = 0; qq < 4; ++qq) {
      float4 d4 = *(const float4*)&Dbuf[row][ssel * 16 + qq * 4];
      float mn = fminf(fminf(d4.x, d4.y), fminf(d4.z, d4.w));
      float worst = (KN == 12) ? td11 : td7;
      if (mn < worst) {
        int gib = m0 + ssel * 16 + qq * 4;
        INS(d4.x, gib + 0)
        INS(d4.y, gib + 1)
        INS(d4.z, gib + 2)
        INS(d4.w, gib + 3)
      }
    }
    __syncthreads();  // selects done before next tile's staging/GEMM overwrite
  }
  // dump named lists; merge the 4 per-wave lists per row; write IDX directly
  const int S = 4 * KN + 1;
  float* cd = &As[0][0];   // 4352 floats >= 64*S
  int* ci = (int*)&Bs[0][0];
  {
    float* cdr = cd + row * S + ssel * KN;
    int* cir = ci + row * S + ssel * KN;
    cdr[0] = td0; cdr[1] = td1; cdr[2] = td2; cdr[3] = td3;
    cdr[4] = td4; cdr[5] = td5; cdr[6] = td6; cdr[7] = td7;
    cir[0] = ti0; cir[1] = ti1; cir[2] = ti2; cir[3] = ti3;
    cir[4] = ti4; cir[5] = ti5; cir[6] = ti6; cir[7] = ti7;
    if (KN == 12) {
      cdr[8] = td8; cdr[9] = td9; cdr[10] = td10; cdr[11] = td11;
      cir[8] = ti8; cir[9] = ti9; cir[10] = ti10; cir[11] = ti11;
    }
  }
  __syncthreads();
  if (tid < 64) {
    int r = tid;
    int p0 = 0, p1 = 0, p2 = 0, p3 = 0;
    const float* cdr = cd + r * S;
    const int* cir = ci + r * S;
    int* op = IDX + ((size_t)b * NPTS + q0 + r) * KN;
    for (int rr = 0; rr < KN; ++rr) {
      float d0 = cdr[0 * KN + p0], d1 = cdr[1 * KN + p1];
      float d2 = cdr[2 * KN + p2], d3 = cdr[3 * KN + p3];
      int i0 = cir[0 * KN + p0], i1 = cir[1 * KN + p1];
      int i2 = cir[2 * KN + p2], i3 = cir[3 * KN + p3];
      int sel = 0; float bdd = d0; int bii = i0;
      if (d1 < bdd || (d1 == bdd && i1 < bii)) { sel = 1; bdd = d1; bii = i1; }
      if (d2 < bdd || (d2 == bdd && i2 < bii)) { sel = 2; bdd = d2; bii = i2; }
      if (d3 < bdd || (d3 == bdd && i3 < bii)) { sel = 3; bdd = d3; bii = i3; }
      op[rr] = bii;
      if (sel == 0) ++p0; else if (sel == 1) ++p1; else if (sel == 2) ++p2; else ++p3;
    }
  }
}
#undef INS
#undef ORD

// ---------------------------------------------------------------- EC1: gather + MLP2 + max
// r10 change: inner product written as pure fmaf chains (16 v_fma per k per
// step). The previous "acc += a+b+c+d" form compiled to mul+fma+fma+fma+add
// (5 instr / 4 MACs, +25% VALU) because fp-contract can't absorb the final
// add without reassociation.
__global__ __launch_bounds__(256) void ec1_kernel(
    const float* __restrict__ UV,   // [P][512] (u | v+b1)
    const int* __restrict__ IDX,    // [P][12]
    const float* __restrict__ W2T,  // [256 c][256 o]
    const float* __restrict__ B2,   // [256]
    float* __restrict__ OUT) {      // [P][256]
  __shared__ __align__(16) float h1[4][12][256];
  int wave = threadIdx.x >> 6;
  int lane = threadIdx.x & 63;
  int p = blockIdx.x * 4 + wave;
  int bbase = (p >> 12) << 12;  // batch start point
  const float* uvb = UV + (size_t)bbase * 512;
  const float* vrow = UV + (size_t)p * 512 + 256;
  float4 v4 = *(const float4*)&vrow[lane * 4];
#pragma unroll
  for (int k = 0; k < 12; ++k) {
    int jn = IDX[p * 12 + k];
    const float* urow = uvb + (size_t)jn * 512;
    float4 u4 = *(const float4*)&urow[lane * 4];
    float4 h;
    h.x = fmaxf(u4.x + v4.x, 0.f); h.y = fmaxf(u4.y + v4.y, 0.f);
    h.z = fmaxf(u4.z + v4.z, 0.f); h.w = fmaxf(u4.w + v4.w, 0.f);
    *(float4*)&h1[wave][k][lane * 4] = h;
  }
  __syncthreads();
  float acc[12][4] = {};
  const float* wbase = W2T + lane * 4;
  for (int c0 = 0; c0 < 256; c0 += 4) {
    float4 w0 = *(const float4*)&wbase[(size_t)(c0 + 0) * 256];
    float4 w1 = *(const float4*)&wbase[(size_t)(c0 + 1) * 256];
    float4 w2 = *(const float4*)&wbase[(size_t)(c0 + 2) * 256];
    float4 w3 = *(const float4*)&wbase[(size_t)(c0 + 3) * 256];
#pragma unroll
    for (int k = 0; k < 12; ++k) {
      float4 h = *(const float4*)&h1[wave][k][c0];  // wave-uniform broadcast
      float a0 = acc[k][0], a1 = acc[k][1], a2 = acc[k][2], a3 = acc[k][3];
      a0 = fmaf(h.x, w0.x, a0); a1 = fmaf(h.x, w0.y, a1);
      a2 = fmaf(h.x, w0.z, a2); a3 = fmaf(h.x, w0.w, a3);
      a0 = fmaf(h.y, w1.x, a0); a1 = fmaf(h.y, w1.y, a1);
      a2 = fmaf(h.y, w1.z, a2); a3 = fmaf(h.y, w1.w, a3);
      a0 = fmaf(h.z, w2.x, a0); a1 = fmaf(h.z, w2.y, a1);
      a2 = fmaf(h.z, w2.z, a2); a3 = fmaf(h.z, w2.w, a3);
      a0 = fmaf(h.w, w3.x, a0); a1 = fmaf(h.w, w3.y, a1);
      a2 = fmaf(h.w, w3.z, a2); a3 = fmaf(h.w, w3.w, a3);
      acc[k][0] = a0; acc[k][1] = a1; acc[k][2] = a2; acc[k][3] = a3;
    }
  }
  float4 b4 = *(const float4*)&B2[lane * 4];
  float m0v = acc[0][0], m1v = acc[0][1], m2v = acc[0][2], m3v = acc[0][3];
#pragma unroll
  for (int k = 1; k < 12; ++k) {
    m0v = fmaxf(m0v, acc[k][0]); m1v = fmaxf(m1v, acc[k][1]);
    m2v = fmaxf(m2v, acc[k][2]); m3v = fmaxf(m3v, acc[k][3]);
  }
  float4 o4;
  o4.x = fmaxf(m0v + b4.x, 0.f); o4.y = fmaxf(m1v + b4.y, 0.f);
  o4.z = fmaxf(m2v + b4.z, 0.f); o4.w = fmaxf(m3v + b4.w, 0.f);
  *(float4*)&OUT[(size_t)p * 256 + lane * 4] = o4;
}

// ---------------------------------------------------------------- EC2: gather + relu + sum
__global__ __launch_bounds__(256) void ec2_kernel(
    const float* __restrict__ UV, const int* __restrict__ IDX,
    float* __restrict__ OUT) {
  int wave = threadIdx.x >> 6;
  int lane = threadIdx.x & 63;
  int p = blockIdx.x * 4 + wave;
  int bbase = (p >> 12) << 12;
  const float* uvb = UV + (size_t)bbase * 512;
  const float* vrow = UV + (size_t)p * 512 + 256;
  float4 v4 = *(const float4*)&vrow[lane * 4];
  float4 a4 = {0.f, 0.f, 0.f, 0.f};
#pragma unroll
  for (int k = 0; k < 8; ++k) {
    int jn = IDX[p * 8 + k];
    const float* urow = uvb + (size_t)jn * 512;
    float4 u4 = *(const float4*)&urow[lane * 4];
    a4.x += fmaxf(u4.x + v4.x, 0.f); a4.y += fmaxf(u4.y + v4.y, 0.f);
    a4.z += fmaxf(u4.z + v4.z, 0.f); a4.w += fmaxf(u4.w + v4.w, 0.f);
  }
  *(float4*)&OUT[(size_t)p * 256 + lane * 4] = a4;
}

// ---------------------------------------------------------------- final 64->1
__global__ void final_kernel(const float* __restrict__ X, const float* __restrict__ W,
                             const float* __restrict__ Bb, float* __restrict__ OUT) {
  int p = blockIdx.x * 4 + (threadIdx.x >> 6);
  int lane = threadIdx.x & 63;
  float v = X[(size_t)p * 64 + lane] * W[lane];
#pragma unroll
  for (int off = 32; off >= 1; off >>= 1) v += __shfl_xor(v, off);
  if (lane == 0) OUT[p] = fmaxf(v + Bb[0], 0.f);
}

// ---------------------------------------------------------------- launch
extern "C" void kernel_launch(void* const* d_in, const int* in_sizes, int n_in,
                              void* d_out, int out_size, void* d_ws, size_t ws_size,
                              hipStream_t stream) {
  const float* feature = (const float*)d_in[0];
  const float* conv0_w = (const float*)d_in[1];
  const float* conv0_b = (const float*)d_in[2];
  const float* ec1_w1  = (const float*)d_in[3];
  const float* ec1_b1  = (const float*)d_in[4];
  const float* ec1_w2  = (const float*)d_in[5];
  const float* ec1_b2  = (const float*)d_in[6];
  const float* conv1_w = (const float*)d_in[7];
  const float* conv1_b = (const float*)d_in[8];
  const float* ec2_w   = (const float*)d_in[9];
  const float* ec2_b   = (const float*)d_in[10];
  const float* dec1_w  = (const float*)d_in[11];
  const float* dec1_b  = (const float*)d_in[12];
  const float* dec2_w  = (const float*)d_in[13];
  const float* dec2_b  = (const float*)d_in[14];
  const float* out_w   = (const float*)d_in[15];
  const float* out_b   = (const float*)d_in[16];
  float* out = (float*)d_out;

  char* ws = (char*)d_ws;
  float* wuv1 = (float*)(ws + 0);
  float* buv1 = (float*)(ws + 131072);
  float* wuv2 = (float*)(ws + 133120);
  float* buv2 = (float*)(ws + 264192);
  float* w2t  = (float*)(ws + 266240);
  float* xx   = (float*)(ws + 528384);
  int*   idx  = (int*)  (ws + 659456);
  float* x0   = (float*)(ws + 2232320);   // x0 -> x1c -> xd2
  float* uv   = (float*)(ws + 10620928);  // uv1 -> uv2 -> xd1
  float* x1   = (float*)(ws + 77729792);  // x1 -> x2

  const int P = PTS_TOTAL;

  prep_kernel<<<256, 256, 0, stream>>>(ec1_w1, ec1_b1, ec1_w2, ec2_w, ec2_b,
                                       wuv1, buv1, wuv2, buv2, w2t);
  gemm_rowmajor<true><<<dim3(P / 64, 1), 256, 0, stream>>>(feature, conv0_w, conv0_b, x0, P, 256, 64);
  sqnorm64<<<P / 4, 256, 0, stream>>>(x0, xx);
  knn_kernel<12><<<dim3(NPTS / 64, NBATCH), 256, 0, stream>>>(x0, xx, idx);
  gemm_rowmajor<false><<<dim3(P / 64, 8), 256, 0, stream>>>(x0, wuv1, buv1, uv, P, 64, 512);
  ec1_kernel<<<P / 4, 256, 0, stream>>>(uv, idx, w2t, ec1_b2, x1);
  gemm_rowmajor<true><<<dim3(P / 64, 1), 256, 0, stream>>>(x1, conv1_w, conv1_b, x0, P, 256, 64);
  sqnorm64<<<P / 4, 256, 0, stream>>>(x0, xx);
  knn_kernel<8><<<dim3(NPTS / 64, NBATCH), 256, 0, stream>>>(x0, xx, idx);
  gemm_rowmajor<false><<<dim3(P / 64, 8), 256, 0, stream>>>(x0, wuv2, buv2, uv, P, 64, 512);
  ec2_kernel<<<P / 4, 256, 0, stream>>>(uv, idx, x1);
  float* xd1 = uv;
  gemm_rowmajor<true><<<dim3(P / 64, 2), 256, 0, stream>>>(x1, dec1_w, dec1_b, xd1, P, 256, 128);
  float* xd2 = x0;
  gemm_rowmajor<true><<<dim3(P / 64, 1), 256, 0, stream>>>(xd1, dec2_w, dec2_b, xd2, P, 128, 64);
  final_kernel<<<P / 4, 256, 0, stream>>>(xd2, out_w, out_b, out);
}